// Round 3
// 474.646 us; speedup vs baseline: 1.0347x; 1.0347x over previous
//
#include <hip/hip_runtime.h>
#include <stdint.h>

#define B 16
#define T 1024
#define V 4096
#define P 100
#define L 128

// Kernel 1: partial scores. 4 waves per (b,p); wave w covers tokens
// [w*256, (w+1)*256). One int4 path read per lane -> 4 independent gathers.
// (log-softmax normalizer cancels in the softmax over p, so it is skipped)
__global__ __launch_bounds__(256) void scores4_kernel(
    const float* __restrict__ emissions,
    const int* __restrict__ emissions_lengths,
    const int* __restrict__ paths,
    float* __restrict__ scores_part)     // (B*P, 4)
{
    int gid = blockIdx.x * blockDim.x + threadIdx.x;
    int wave = gid >> 6;
    int lane = threadIdx.x & 63;
    if (wave >= B * P * 4) return;
    int w  = wave & 3;
    int bp = wave >> 2;
    int b  = bp / P;
    int len = emissions_lengths[b];
    const int4* path4 = (const int4*)(paths + (size_t)bp * T);
    int4 tk = path4[w * 64 + lane];              // coalesced 16B, tokens 4i..4i+3
    int tbase = 4 * (w * 64 + lane);
    const float* em = emissions + (size_t)b * T * V;

    float acc = 0.f;
    if (tbase + 0 < len) acc += em[(size_t)(tbase + 0) * V + tk.x];
    if (tbase + 1 < len) acc += em[(size_t)(tbase + 1) * V + tk.y];
    if (tbase + 2 < len) acc += em[(size_t)(tbase + 2) * V + tk.z];
    if (tbase + 3 < len) acc += em[(size_t)(tbase + 3) * V + tk.w];

    #pragma unroll
    for (int off = 32; off; off >>= 1) acc += __shfl_down(acc, off, 64);
    if (lane == 0) scores_part[bp * 4 + w] = acc;
}

// Kernel 2: wers[b,p] via anti-diagonal Levenshtein DP.
// Phase 1: CTC-collapse valid tokens into LDS (per-wave slot).
// Phase 2: diagonal sweep; lane i owns columns j1=2i+1, j2=2i+2.
// v2: the per-diagonal neighbor exchange uses DPP wave_shr:1 (one VALU op)
// instead of __shfl_up (ds_bpermute, ~120cy LDS latency on the critical
// chain, and its lgkmcnt wait also drained the token ds_read). Token
// fetches are unrolled x4 with a 4-iteration prefetch distance so their
// LDS latency is off the dependency chain.
__global__ __launch_bounds__(256) void wer_kernel(
    const int* __restrict__ emissions_lengths,
    const int* __restrict__ labels,
    const int* __restrict__ labels_length,
    const int* __restrict__ paths,
    float* __restrict__ wers)
{
    __shared__ unsigned short toks[4][1024];
    int gid = blockIdx.x * blockDim.x + threadIdx.x;
    int wave = gid >> 6;
    int lane = threadIdx.x & 63;
    int slot = (threadIdx.x >> 6) & 3;
    if (wave >= B * P) return;
    int b = wave / P;
    int len = emissions_lengths[b];
    int ll  = labels_length[b];
    const int* path = paths + (size_t)wave * T;

    // ---- Phase 1: compact CTC-valid tokens ----
    int prev_last = -1;
    int base = 0;
    for (int t0 = 0; t0 < len; t0 += 64) {
        int c = path[t0 + lane];
        // wave_shr:1 : lane i <- lane i-1 (lane 0 gets 0, overwritten below)
        int cp = __builtin_amdgcn_update_dpp(0, c, 0x138, 0xF, 0xF, true);
        if (lane == 0) cp = prev_last;
        bool valid = (c != 0) && (c != cp) && (t0 + lane < len);
        unsigned long long mask = __ballot(valid);
        int pos = base + __popcll(mask & ((1ull << lane) - 1ull));
        if (valid) toks[slot][pos] = (unsigned short)c;
        base += __popcll(mask);
        prev_last = __builtin_amdgcn_readlane(c, 63);
    }
    int S = base;                                 // compacted length

    // ---- Phase 2: diagonal DP ----
    int j1 = 2 * lane + 1;
    int j2 = 2 * lane + 2;
    int r1 = labels[b * L + 2 * lane];
    int r2 = labels[b * L + 2 * lane + 1];

    int A1 = j1, B1 = j1;                         // col j1: diag d-1, d-2 values
    int A2 = j2, B2 = j2;                         // col j2
    int tok1 = 0, tok2 = 0;
    int dmax = S + ll;
    const unsigned short* tk = toks[slot];
    int tb = -2 * lane - 2;                       // token idx for diag d is d+tb

    // One diagonal step. DP values are nonnegative and < 2048, so (A2,B2)
    // pack into one 32-bit word for a single-DPP exchange.
    auto step = [&](int d, int newtok) {
        int packed = (A2 << 16) | B2;
        int up = __builtin_amdgcn_update_dpp(0, packed, 0x138, 0xF, 0xF, true);
        int upA = lane ? (int)(((unsigned)up) >> 16) : (d - 1);   // col 0: D[t][0]=t
        int upB = lane ? (up & 0xffff)               : (d - 2);
        tok2 = tok1;
        tok1 = newtok;
        int t1 = d - j1;
        int n1 = min(min(A1, upA) + 1, upB + (tok1 != r1));
        n1 = (t1 <= 0) ? j1 : ((t1 > S) ? A1 : n1);   // boundary / freeze at D[S][j1]
        int t2 = d - j2;
        int n2 = min(min(A2, A1) + 1, B1 + (tok2 != r2));
        n2 = (t2 <= 0) ? j2 : ((t2 > S) ? A2 : n2);
        B1 = A1; A1 = n1;
        B2 = A2; A2 = n2;
    };

    // Tokens for d=1..4; prefetch next 4 each block (distance ~4 iters).
    int c0 = tk[(1 + tb) & 1023];
    int c1 = tk[(2 + tb) & 1023];
    int c2 = tk[(3 + tb) & 1023];
    int c3 = tk[(4 + tb) & 1023];
    // Overrun past dmax (up to 3 steps) is safe: t>S freezes cells and
    // columns j>ll never feed columns <=ll.
    for (int d = 1; d <= dmax; d += 4) {
        int p0 = tk[(d + 4 + tb) & 1023];
        int p1 = tk[(d + 5 + tb) & 1023];
        int p2 = tk[(d + 6 + tb) & 1023];
        int p3 = tk[(d + 7 + tb) & 1023];
        step(d + 0, c0);
        step(d + 1, c1);
        step(d + 2, c2);
        step(d + 3, c3);
        c0 = p0; c1 = p1; c2 = p2; c3 = p3;
    }

    int va = __shfl(A1, (ll - 1) >> 1, 64);       // ll odd  -> column ll = j1
    int vb = __shfl(A2, (ll - 2) >> 1, 64);       // ll even -> column ll = j2
    int res = (ll & 1) ? va : vb;                 // setup guarantees ll >= 64
    if (lane == 0) wers[wave] = (float)res;
}

// Kernel 3: out = sum_b sum_p softmax_p(scores[b,:])[p] * wers[b,p]
__global__ __launch_bounds__(1024) void reduce_kernel(
    const float* __restrict__ scores_part,        // (B*P, 4)
    const float* __restrict__ wers,
    float* __restrict__ out)
{
    __shared__ float contrib[B];
    int lane = threadIdx.x & 63;
    int b = threadIdx.x >> 6;                     // 16 waves, one per batch

    int p1 = b * P + lane;
    float s1 = scores_part[p1 * 4 + 0] + scores_part[p1 * 4 + 1]
             + scores_part[p1 * 4 + 2] + scores_part[p1 * 4 + 3];
    float w1 = wers[p1];
    bool has2 = lane < (P - 64);
    int p2 = b * P + 64 + (has2 ? lane : 0);
    float s2 = has2 ? (scores_part[p2 * 4 + 0] + scores_part[p2 * 4 + 1]
                     + scores_part[p2 * 4 + 2] + scores_part[p2 * 4 + 3])
                    : -3.4e38f;
    float w2 = has2 ? wers[p2] : 0.f;

    float m = fmaxf(s1, s2);
    #pragma unroll
    for (int off = 32; off; off >>= 1) m = fmaxf(m, __shfl_xor(m, off, 64));
    float e1 = expf(s1 - m);
    float e2 = has2 ? expf(s2 - m) : 0.f;
    float num = e1 * w1 + e2 * w2;
    float den = e1 + e2;
    #pragma unroll
    for (int off = 32; off; off >>= 1) {
        num += __shfl_xor(num, off, 64);
        den += __shfl_xor(den, off, 64);
    }
    if (lane == 0) contrib[b] = num / den;
    __syncthreads();
    if (threadIdx.x == 0) {
        float s = 0.f;
        #pragma unroll
        for (int i = 0; i < B; i++) s += contrib[i];
        out[0] = s;
    }
}

extern "C" void kernel_launch(void* const* d_in, const int* in_sizes, int n_in,
                              void* d_out, int out_size, void* d_ws, size_t ws_size,
                              hipStream_t stream) {
    const float* emissions          = (const float*)d_in[0];
    const int*   emissions_lengths  = (const int*)d_in[1];
    const int*   labels             = (const int*)d_in[2];
    const int*   labels_length      = (const int*)d_in[3];
    const int*   paths              = (const int*)d_in[4];
    float* out = (float*)d_out;

    float* scores_part = (float*)d_ws;            // B*P*4 floats
    float* wers        = scores_part + B * P * 4; // B*P floats

    scores4_kernel<<<(B * P * 4 * 64) / 256, 256, 0, stream>>>(
        emissions, emissions_lengths, paths, scores_part);
    wer_kernel<<<(B * P * 64) / 256, 256, 0, stream>>>(
        emissions_lengths, labels, labels_length, paths, wers);
    reduce_kernel<<<1, 1024, 0, stream>>>(scores_part, wers, out);
}

// Round 4
// 453.066 us; speedup vs baseline: 1.0840x; 1.0476x over previous
//
#include <hip/hip_runtime.h>
#include <stdint.h>

#define B 16
#define T 1024
#define V 4096
#define P 100
#define L 128

// Kernel 1: partial scores. 4 waves per (b,p); wave w covers tokens
// [w*256, (w+1)*256). One int4 path read per lane -> 4 independent gathers.
// v2: XCD-locality swizzle. 1600 blocks round-robin across 8 XCDs by
// default, so all 8 per-XCD L2s re-fetched the same emission rows (~8x
// HBM amplification -> ~157us). Remap so XCD k gets original blocks
// [200k,200k+200) = exactly 2 b's (2 x 16MB row sets, reused by all 100
// paths; concurrent window fits 4MB L2). 1600%8==0 -> bijective.
__global__ __launch_bounds__(256) void scores4_kernel(
    const float* __restrict__ emissions,
    const int* __restrict__ emissions_lengths,
    const int* __restrict__ paths,
    float* __restrict__ scores_part)     // (B*P, 4)
{
    int bp = 200 * (blockIdx.x & 7) + (blockIdx.x >> 3);  // original block id
    int w  = threadIdx.x >> 6;
    int lane = threadIdx.x & 63;
    int b  = bp / P;
    int len = emissions_lengths[b];
    const int4* path4 = (const int4*)(paths + (size_t)bp * T);
    int4 tk = path4[w * 64 + lane];              // coalesced 16B, tokens 4i..4i+3
    int tbase = 4 * (w * 64 + lane);
    const float* em = emissions + (size_t)b * T * V;

    float acc = 0.f;
    if (tbase + 0 < len) acc += em[(size_t)(tbase + 0) * V + tk.x];
    if (tbase + 1 < len) acc += em[(size_t)(tbase + 1) * V + tk.y];
    if (tbase + 2 < len) acc += em[(size_t)(tbase + 2) * V + tk.z];
    if (tbase + 3 < len) acc += em[(size_t)(tbase + 3) * V + tk.w];

    #pragma unroll
    for (int off = 32; off; off >>= 1) acc += __shfl_down(acc, off, 64);
    if (lane == 0) scores_part[bp * 4 + w] = acc;
}

// Kernel 2: wers[b,p] via anti-diagonal Levenshtein DP.
// v3 (latency-bound fix; v2's DPP gave only ~16us because the kernel is
// dep-CHAIN-bound at ~1.5 waves/SIMD, ~8cy/dependent-VALU):
//  - TWO problems per wave (same b -> shared refs/ll): two independent
//    chains interleave -> issue-bound; 800 waves, 200 blocks (<=1 round).
//  - Freeze select (t>S) dropped: cells with t<=S are never fed by t>S
//    cells (deps only from t-1/t), so garbage past t=S can't reach the
//    harvest cone. Result captured at wave-uniform d == S+ll snapshot.
//  - Boundary selects (t<=0) replaced by one max(n, 2j-d) clamp: exact
//    at t=0, and for t>=1 it's the inert lower bound D[t][j] >= j-t.
//  - Phase-1 path chunks preloaded upfront (16 independent loads) so the
//    serial ballot loop doesn't eat 16 HBM latencies.
#define STEP(S, d, newtok) do {                                              \
    int packed = (A2##S << 16) | B2##S;                                      \
    int up = __builtin_amdgcn_update_dpp(0, packed, 0x138, 0xF, 0xF, true);  \
    int upA = lane ? (int)(((unsigned)up) >> 16) : ((d) - 1);                \
    int upB = lane ? (up & 0xffff)               : ((d) - 2);                \
    tok2##S = tok1##S; tok1##S = (newtok);                                   \
    int n1 = min(min(A1##S, upA) + 1, upB + (tok1##S != r1));                \
    n1 = max(n1, cj1 - (d));                                                 \
    int n2 = min(min(A2##S, A1##S) + 1, B1##S + (tok2##S != r2));            \
    n2 = max(n2, cj2 - (d));                                                 \
    B1##S = A1##S; A1##S = n1; B2##S = A2##S; A2##S = n2;                    \
} while (0)

#define CAP(S, d) do { if ((d) == dmax##S) { rA1##S = A1##S; rA2##S = A2##S; } } while (0)

__global__ __launch_bounds__(256) void wer_kernel(
    const int* __restrict__ emissions_lengths,
    const int* __restrict__ labels,
    const int* __restrict__ labels_length,
    const int* __restrict__ paths,
    float* __restrict__ wers)
{
    __shared__ unsigned short toks[8][1024];
    int wid  = blockIdx.x * 4 + (threadIdx.x >> 6);   // 0..799, one pair each
    int lane = threadIdx.x & 63;
    int b = wid / (P / 2);
    int q = wid % (P / 2);
    int len = emissions_lengths[b];
    int ll  = labels_length[b];
    const int* pathA = paths + (size_t)(b * P + 2 * q) * T;
    const int* pathB = pathA + T;
    unsigned short* tkA = toks[(threadIdx.x >> 6) * 2 + 0];
    unsigned short* tkB = toks[(threadIdx.x >> 6) * 2 + 1];
    unsigned long long lt = (1ull << lane) - 1ull;

    // ---- Phase 1: compact CTC-valid tokens (x2, loads preissued) ----
    auto compact = [&](const int* __restrict__ path,
                       unsigned short* __restrict__ dst) -> int {
        int c[16];
        #pragma unroll
        for (int k = 0; k < 16; k++) c[k] = path[k * 64 + lane];
        int prev_last = -1, base = 0;
        #pragma unroll
        for (int k = 0; k < 16; k++) {
            int cc = c[k];
            int cp = __builtin_amdgcn_update_dpp(0, cc, 0x138, 0xF, 0xF, true);
            if (lane == 0) cp = prev_last;
            bool valid = (cc != 0) && (cc != cp) && (k * 64 + lane < len);
            unsigned long long mask = __ballot(valid);
            int pos = base + __popcll(mask & lt);
            if (valid) dst[pos] = (unsigned short)cc;
            base += __popcll(mask);
            prev_last = __builtin_amdgcn_readlane(cc, 63);
        }
        return base;
    };
    int Sa = compact(pathA, tkA);
    int Sb = compact(pathB, tkB);

    // ---- Phase 2: diagonal DP, two interleaved problems ----
    int j1 = 2 * lane + 1;
    int j2 = 2 * lane + 2;
    int r1 = labels[b * L + 2 * lane];
    int r2 = labels[b * L + 2 * lane + 1];
    int cj1 = 2 * j1;                              // clamp: j1 - t1 = 2*j1 - d
    int cj2 = 2 * j2;
    int tb = -2 * lane - 2;                        // token idx for diag d is d+tb

    int A1a = j1, B1a = j1, A2a = j2, B2a = j2, tok1a = 0, tok2a = 0;
    int A1b = j1, B1b = j1, A2b = j2, B2b = j2, tok1b = 0, tok2b = 0;
    int rA1a = j1, rA2a = j2, rA1b = j1, rA2b = j2;
    int dmaxa = Sa + ll;
    int dmaxb = Sb + ll;
    int dmax = max(dmaxa, dmaxb);

    int ca0 = tkA[(1 + tb) & 1023], ca1 = tkA[(2 + tb) & 1023];
    int ca2 = tkA[(3 + tb) & 1023], ca3 = tkA[(4 + tb) & 1023];
    int cb0 = tkB[(1 + tb) & 1023], cb1 = tkB[(2 + tb) & 1023];
    int cb2 = tkB[(3 + tb) & 1023], cb3 = tkB[(4 + tb) & 1023];

    // Overrun past each problem's dmax is harmless: results snapshot at
    // the exact d == dmax diagonal (wave-uniform branch, off-chain).
    for (int d = 1; d <= dmax; d += 4) {
        int pa0 = tkA[(d + 4 + tb) & 1023];
        int pa1 = tkA[(d + 5 + tb) & 1023];
        int pa2 = tkA[(d + 6 + tb) & 1023];
        int pa3 = tkA[(d + 7 + tb) & 1023];
        int pb0 = tkB[(d + 4 + tb) & 1023];
        int pb1 = tkB[(d + 5 + tb) & 1023];
        int pb2 = tkB[(d + 6 + tb) & 1023];
        int pb3 = tkB[(d + 7 + tb) & 1023];
        STEP(a, d + 0, ca0); STEP(b, d + 0, cb0); CAP(a, d + 0); CAP(b, d + 0);
        STEP(a, d + 1, ca1); STEP(b, d + 1, cb1); CAP(a, d + 1); CAP(b, d + 1);
        STEP(a, d + 2, ca2); STEP(b, d + 2, cb2); CAP(a, d + 2); CAP(b, d + 2);
        STEP(a, d + 3, ca3); STEP(b, d + 3, cb3); CAP(a, d + 3); CAP(b, d + 3);
        ca0 = pa0; ca1 = pa1; ca2 = pa2; ca3 = pa3;
        cb0 = pb0; cb1 = pb1; cb2 = pb2; cb3 = pb3;
    }

    int vaa = __shfl(rA1a, (ll - 1) >> 1, 64);    // ll odd  -> column ll = j1
    int vba = __shfl(rA2a, (ll - 2) >> 1, 64);    // ll even -> column ll = j2
    int resa = (ll & 1) ? vaa : vba;              // setup guarantees ll >= 64
    int vab = __shfl(rA1b, (ll - 1) >> 1, 64);
    int vbb = __shfl(rA2b, (ll - 2) >> 1, 64);
    int resb = (ll & 1) ? vab : vbb;
    if (lane == 0) {
        wers[b * P + 2 * q + 0] = (float)resa;
        wers[b * P + 2 * q + 1] = (float)resb;
    }
}

// Kernel 3: out = sum_b sum_p softmax_p(scores[b,:])[p] * wers[b,p]
__global__ __launch_bounds__(1024) void reduce_kernel(
    const float* __restrict__ scores_part,        // (B*P, 4)
    const float* __restrict__ wers,
    float* __restrict__ out)
{
    __shared__ float contrib[B];
    int lane = threadIdx.x & 63;
    int b = threadIdx.x >> 6;                     // 16 waves, one per batch

    int p1 = b * P + lane;
    float s1 = scores_part[p1 * 4 + 0] + scores_part[p1 * 4 + 1]
             + scores_part[p1 * 4 + 2] + scores_part[p1 * 4 + 3];
    float w1 = wers[p1];
    bool has2 = lane < (P - 64);
    int p2 = b * P + 64 + (has2 ? lane : 0);
    float s2 = has2 ? (scores_part[p2 * 4 + 0] + scores_part[p2 * 4 + 1]
                     + scores_part[p2 * 4 + 2] + scores_part[p2 * 4 + 3])
                    : -3.4e38f;
    float w2 = has2 ? wers[p2] : 0.f;

    float m = fmaxf(s1, s2);
    #pragma unroll
    for (int off = 32; off; off >>= 1) m = fmaxf(m, __shfl_xor(m, off, 64));
    float e1 = expf(s1 - m);
    float e2 = has2 ? expf(s2 - m) : 0.f;
    float num = e1 * w1 + e2 * w2;
    float den = e1 + e2;
    #pragma unroll
    for (int off = 32; off; off >>= 1) {
        num += __shfl_xor(num, off, 64);
        den += __shfl_xor(den, off, 64);
    }
    if (lane == 0) contrib[b] = num / den;
    __syncthreads();
    if (threadIdx.x == 0) {
        float s = 0.f;
        #pragma unroll
        for (int i = 0; i < B; i++) s += contrib[i];
        out[0] = s;
    }
}

extern "C" void kernel_launch(void* const* d_in, const int* in_sizes, int n_in,
                              void* d_out, int out_size, void* d_ws, size_t ws_size,
                              hipStream_t stream) {
    const float* emissions          = (const float*)d_in[0];
    const int*   emissions_lengths  = (const int*)d_in[1];
    const int*   labels             = (const int*)d_in[2];
    const int*   labels_length      = (const int*)d_in[3];
    const int*   paths              = (const int*)d_in[4];
    float* out = (float*)d_out;

    float* scores_part = (float*)d_ws;            // B*P*4 floats
    float* wers        = scores_part + B * P * 4; // B*P floats

    scores4_kernel<<<(B * P * 4 * 64) / 256, 256, 0, stream>>>(
        emissions, emissions_lengths, paths, scores_part);
    wer_kernel<<<(B * P / 2 * 64) / 256, 256, 0, stream>>>(
        emissions_lengths, labels, labels_length, paths, wers);
    reduce_kernel<<<1, 1024, 0, stream>>>(scores_part, wers, out);
}

// Round 5
// 445.815 us; speedup vs baseline: 1.1016x; 1.0163x over previous
//
#include <hip/hip_runtime.h>
#include <stdint.h>

#define B 16
#define T 1024
#define V 4096
#define P 100
#define L 128

// wer DP step macros (unchanged from round 4, verified absmax=0).
#define STEP(S, d, newtok) do {                                              \
    int packed = (A2##S << 16) | B2##S;                                      \
    int up = __builtin_amdgcn_update_dpp(0, packed, 0x138, 0xF, 0xF, true);  \
    int upA = lane ? (int)(((unsigned)up) >> 16) : ((d) - 1);                \
    int upB = lane ? (up & 0xffff)               : ((d) - 2);                \
    tok2##S = tok1##S; tok1##S = (newtok);                                   \
    int n1 = min(min(A1##S, upA) + 1, upB + (tok1##S != r1));                \
    n1 = max(n1, cj1 - (d));                                                 \
    int n2 = min(min(A2##S, A1##S) + 1, B1##S + (tok2##S != r2));            \
    n2 = max(n2, cj2 - (d));                                                 \
    B1##S = A1##S; A1##S = n1; B2##S = A2##S; A2##S = n2;                    \
} while (0)

#define CAP(S, d) do { if ((d) == dmax##S) { rA1##S = A1##S; rA2##S = A2##S; } } while (0)

// Fused kernel: scores (blocks 0..1599) and wer (blocks 1600..1799) are
// data-independent, so they run as disjoint block ranges of ONE dispatch
// instead of serialized dispatches: total = max(s,w) not s+w, and the
// fused dispatch is big enough to surface in the profiler's top-5 with
// counters (attribution: FETCH_SIZE>>100MB -> scores-bound; VALUBusy
// high + FETCH ~100MB -> wer-bound). Internals of both paths are
// byte-identical to round 4.
__global__ __launch_bounds__(256) void fused_kernel(
    const float* __restrict__ emissions,
    const int* __restrict__ emissions_lengths,
    const int* __restrict__ labels,
    const int* __restrict__ labels_length,
    const int* __restrict__ paths,
    float* __restrict__ scores_part,     // (B*P, 4)
    float* __restrict__ wers)            // (B*P)
{
    int lane = threadIdx.x & 63;
    if (blockIdx.x < 1600) {
        // ---- scores path: 4 waves per (b,p); wave w covers 256 tokens.
        // XCD-locality swizzle: XCD k gets original blocks [200k,200k+200)
        // = exactly 2 b's, reused by all 100 paths. 1600%8==0 -> bijective.
        int bp = 200 * (blockIdx.x & 7) + (blockIdx.x >> 3);
        int w  = threadIdx.x >> 6;
        int b  = bp / P;
        int len = emissions_lengths[b];
        const int4* path4 = (const int4*)(paths + (size_t)bp * T);
        int4 tk = path4[w * 64 + lane];          // coalesced 16B, tokens 4i..4i+3
        int tbase = 4 * (w * 64 + lane);
        const float* em = emissions + (size_t)b * T * V;

        float acc = 0.f;
        if (tbase + 0 < len) acc += em[(size_t)(tbase + 0) * V + tk.x];
        if (tbase + 1 < len) acc += em[(size_t)(tbase + 1) * V + tk.y];
        if (tbase + 2 < len) acc += em[(size_t)(tbase + 2) * V + tk.z];
        if (tbase + 3 < len) acc += em[(size_t)(tbase + 3) * V + tk.w];

        #pragma unroll
        for (int off = 32; off; off >>= 1) acc += __shfl_down(acc, off, 64);
        if (lane == 0) scores_part[bp * 4 + w] = acc;
        return;
    }

    // ---- wer path: anti-diagonal Levenshtein DP, two problems per wave
    // (same b -> shared refs/ll); DPP wave_shr:1 neighbor exchange; no
    // freeze select (t>S garbage can't reach the harvest cone; snapshot
    // at wave-uniform d==dmax); boundary via max(n, 2j-d) clamp; path
    // chunks preloaded upfront.
    __shared__ unsigned short toks[8][1024];
    int wblk = blockIdx.x - 1600;
    int wid  = wblk * 4 + (threadIdx.x >> 6);     // 0..799, one pair each
    int b = wid / (P / 2);
    int q = wid % (P / 2);
    int len = emissions_lengths[b];
    int ll  = labels_length[b];
    const int* pathA = paths + (size_t)(b * P + 2 * q) * T;
    const int* pathB = pathA + T;
    unsigned short* tkA = toks[(threadIdx.x >> 6) * 2 + 0];
    unsigned short* tkB = toks[(threadIdx.x >> 6) * 2 + 1];
    unsigned long long lt = (1ull << lane) - 1ull;

    // Phase 1: compact CTC-valid tokens (x2, loads preissued)
    auto compact = [&](const int* __restrict__ path,
                       unsigned short* __restrict__ dst) -> int {
        int c[16];
        #pragma unroll
        for (int k = 0; k < 16; k++) c[k] = path[k * 64 + lane];
        int prev_last = -1, base = 0;
        #pragma unroll
        for (int k = 0; k < 16; k++) {
            int cc = c[k];
            int cp = __builtin_amdgcn_update_dpp(0, cc, 0x138, 0xF, 0xF, true);
            if (lane == 0) cp = prev_last;
            bool valid = (cc != 0) && (cc != cp) && (k * 64 + lane < len);
            unsigned long long mask = __ballot(valid);
            int pos = base + __popcll(mask & lt);
            if (valid) dst[pos] = (unsigned short)cc;
            base += __popcll(mask);
            prev_last = __builtin_amdgcn_readlane(cc, 63);
        }
        return base;
    };
    int Sa = compact(pathA, tkA);
    int Sb = compact(pathB, tkB);

    // Phase 2: diagonal DP, two interleaved problems
    int j1 = 2 * lane + 1;
    int j2 = 2 * lane + 2;
    int r1 = labels[b * L + 2 * lane];
    int r2 = labels[b * L + 2 * lane + 1];
    int cj1 = 2 * j1;                              // clamp: j1 - t1 = 2*j1 - d
    int cj2 = 2 * j2;
    int tb = -2 * lane - 2;                        // token idx for diag d is d+tb

    int A1a = j1, B1a = j1, A2a = j2, B2a = j2, tok1a = 0, tok2a = 0;
    int A1b = j1, B1b = j1, A2b = j2, B2b = j2, tok1b = 0, tok2b = 0;
    int rA1a = j1, rA2a = j2, rA1b = j1, rA2b = j2;
    int dmaxa = Sa + ll;
    int dmaxb = Sb + ll;
    int dmax = max(dmaxa, dmaxb);

    int ca0 = tkA[(1 + tb) & 1023], ca1 = tkA[(2 + tb) & 1023];
    int ca2 = tkA[(3 + tb) & 1023], ca3 = tkA[(4 + tb) & 1023];
    int cb0 = tkB[(1 + tb) & 1023], cb1 = tkB[(2 + tb) & 1023];
    int cb2 = tkB[(3 + tb) & 1023], cb3 = tkB[(4 + tb) & 1023];

    for (int d = 1; d <= dmax; d += 4) {
        int pa0 = tkA[(d + 4 + tb) & 1023];
        int pa1 = tkA[(d + 5 + tb) & 1023];
        int pa2 = tkA[(d + 6 + tb) & 1023];
        int pa3 = tkA[(d + 7 + tb) & 1023];
        int pb0 = tkB[(d + 4 + tb) & 1023];
        int pb1 = tkB[(d + 5 + tb) & 1023];
        int pb2 = tkB[(d + 6 + tb) & 1023];
        int pb3 = tkB[(d + 7 + tb) & 1023];
        STEP(a, d + 0, ca0); STEP(b, d + 0, cb0); CAP(a, d + 0); CAP(b, d + 0);
        STEP(a, d + 1, ca1); STEP(b, d + 1, cb1); CAP(a, d + 1); CAP(b, d + 1);
        STEP(a, d + 2, ca2); STEP(b, d + 2, cb2); CAP(a, d + 2); CAP(b, d + 2);
        STEP(a, d + 3, ca3); STEP(b, d + 3, cb3); CAP(a, d + 3); CAP(b, d + 3);
        ca0 = pa0; ca1 = pa1; ca2 = pa2; ca3 = pa3;
        cb0 = pb0; cb1 = pb1; cb2 = pb2; cb3 = pb3;
    }

    int vaa = __shfl(rA1a, (ll - 1) >> 1, 64);    // ll odd  -> column ll = j1
    int vba = __shfl(rA2a, (ll - 2) >> 1, 64);    // ll even -> column ll = j2
    int resa = (ll & 1) ? vaa : vba;              // setup guarantees ll >= 64
    int vab = __shfl(rA1b, (ll - 1) >> 1, 64);
    int vbb = __shfl(rA2b, (ll - 2) >> 1, 64);
    int resb = (ll & 1) ? vab : vbb;
    if (lane == 0) {
        wers[b * P + 2 * q + 0] = (float)resa;
        wers[b * P + 2 * q + 1] = (float)resb;
    }
}

// Kernel 3: out = sum_b sum_p softmax_p(scores[b,:])[p] * wers[b,p]
__global__ __launch_bounds__(1024) void reduce_kernel(
    const float* __restrict__ scores_part,        // (B*P, 4)
    const float* __restrict__ wers,
    float* __restrict__ out)
{
    __shared__ float contrib[B];
    int lane = threadIdx.x & 63;
    int b = threadIdx.x >> 6;                     // 16 waves, one per batch

    int p1 = b * P + lane;
    float s1 = scores_part[p1 * 4 + 0] + scores_part[p1 * 4 + 1]
             + scores_part[p1 * 4 + 2] + scores_part[p1 * 4 + 3];
    float w1 = wers[p1];
    bool has2 = lane < (P - 64);
    int p2 = b * P + 64 + (has2 ? lane : 0);
    float s2 = has2 ? (scores_part[p2 * 4 + 0] + scores_part[p2 * 4 + 1]
                     + scores_part[p2 * 4 + 2] + scores_part[p2 * 4 + 3])
                    : -3.4e38f;
    float w2 = has2 ? wers[p2] : 0.f;

    float m = fmaxf(s1, s2);
    #pragma unroll
    for (int off = 32; off; off >>= 1) m = fmaxf(m, __shfl_xor(m, off, 64));
    float e1 = expf(s1 - m);
    float e2 = has2 ? expf(s2 - m) : 0.f;
    float num = e1 * w1 + e2 * w2;
    float den = e1 + e2;
    #pragma unroll
    for (int off = 32; off; off >>= 1) {
        num += __shfl_xor(num, off, 64);
        den += __shfl_xor(den, off, 64);
    }
    if (lane == 0) contrib[b] = num / den;
    __syncthreads();
    if (threadIdx.x == 0) {
        float s = 0.f;
        #pragma unroll
        for (int i = 0; i < B; i++) s += contrib[i];
        out[0] = s;
    }
}

extern "C" void kernel_launch(void* const* d_in, const int* in_sizes, int n_in,
                              void* d_out, int out_size, void* d_ws, size_t ws_size,
                              hipStream_t stream) {
    const float* emissions          = (const float*)d_in[0];
    const int*   emissions_lengths  = (const int*)d_in[1];
    const int*   labels             = (const int*)d_in[2];
    const int*   labels_length      = (const int*)d_in[3];
    const int*   paths              = (const int*)d_in[4];
    float* out = (float*)d_out;

    float* scores_part = (float*)d_ws;            // B*P*4 floats
    float* wers        = scores_part + B * P * 4; // B*P floats

    fused_kernel<<<1800, 256, 0, stream>>>(
        emissions, emissions_lengths, labels, labels_length, paths,
        scores_part, wers);
    reduce_kernel<<<1, 1024, 0, stream>>>(scores_part, wers, out);
}